// Round 3
// baseline (485.363 us; speedup 1.0000x reference)
//
#include <hip/hip_runtime.h>
#include <stdint.h>

// Problem constants
#define NN   1000000      // NUM_NODES
#define DD   128          // MEM_DIM == MSG_DIM
#define BT   262144       // batch B
#define TR   32           // rows per LDS tile
#define NT   8            // tiles per block
#define RPB  (TR * NT)    // 256 batch rows per GRU block
#define GRUB (BT / RPB)   // 1024 GRU blocks
#define CPYB 2048         // copy blocks
#define GRID (GRUB + CPYB) // 3072 total, role = blockIdx.x % 3

typedef __attribute__((ext_vector_type(8))) short bf16x8;  // 8 bf16 in 4 VGPRs
typedef __attribute__((ext_vector_type(4))) float f32x4;

__device__ __forceinline__ unsigned short f2bf(float f) {
    union { float f; uint32_t u; } c; c.f = f;
    uint32_t u = c.u + 0x7FFFu + ((c.u >> 16) & 1u);  // RNE
    return (unsigned short)(u >> 16);
}
__device__ __forceinline__ float bf2f(unsigned short s) {
    union { uint32_t u; float f; } c; c.u = ((uint32_t)s) << 16;
    return c.f;
}
__device__ __forceinline__ float sigmoid_f(float x) {
    return 1.0f / (1.0f + __expf(-x));
}
__device__ __forceinline__ float tanh_f(float x) {
    return 2.0f / (1.0f + __expf(-2.0f * x)) - 1.0f;
}
__device__ __forceinline__ bf16x8 cvt8(float4 a, float4 b) {
    bf16x8 v;
    v[0] = (short)f2bf(a.x); v[1] = (short)f2bf(a.y);
    v[2] = (short)f2bf(a.z); v[3] = (short)f2bf(a.w);
    v[4] = (short)f2bf(b.x); v[5] = (short)f2bf(b.y);
    v[6] = (short)f2bf(b.z); v[7] = (short)f2bf(b.w);
    return v;
}

// ---------------------------------------------------------------------------
// winner[] = -1 (replaces rocclr fillBuffer node)
__global__ __launch_bounds__(256) void k_init(int4* __restrict__ winner) {
    int i = blockIdx.x * 256 + threadIdx.x;
    if (i < NN / 4) winner[i] = make_int4(-1, -1, -1, -1);
}

// last-occurrence-wins winner per node
__global__ __launch_bounds__(256) void k_winner(const int* __restrict__ node_ids,
                                                int* __restrict__ winner) {
    int i = blockIdx.x * 256 + threadIdx.x;
    if (i < BT) atomicMax(&winner[node_ids[i]], i);
}

// ---------------------------------------------------------------------------
// Fused kernel. role 0 (1024 blocks): gather + GRU (bf16 MFMA) + gated scatter.
// roles 1,2 (2048 blocks): stream-copy memory rows w/o winner + last_update.
// GRU geometry: 512 thr = 8 waves; wave w owns output cols [16w,16w+16) with
// all 24 weight B-fragments register-resident. 8 row-tiles of 32 rows staged
// in double-buffered XOR-swizzled LDS (bf16), prefetch depth 2.
// mfma_f32_16x16x32_bf16: A[r][k]: r=lane&15, k=8*(lane>>4)+e
//                         B[k][n]: n=lane&15, same k
//                         D[r][c]: c=lane&15, r=4*(lane>>4)+q
__global__ __launch_bounds__(512, 1) void k_fused(
        const float* __restrict__ memory,
        const float* __restrict__ messages,
        const float* __restrict__ W_ih,
        const float* __restrict__ W_hh,
        const float* __restrict__ b_ih,
        const float* __restrict__ b_hh,
        const int*   __restrict__ node_ids,
        const int*   __restrict__ winner,
        const float* __restrict__ lu_in,
        const float* __restrict__ ts,
        float* __restrict__ out_mem,
        float* __restrict__ out_lu) {
    __shared__ unsigned short x_lds[2][TR * DD];   // 2 x 8 KB, swizzled
    __shared__ unsigned short h_lds[2][TR * DD];   // 2 x 8 KB, swizzled
    __shared__ int s_nid[RPB];
    __shared__ unsigned char s_win[RPB];

    const int tid  = threadIdx.x;
    const int role = blockIdx.x % 3;

    if (role != 0) {
        // ---------------- copy role ----------------
        const int cid = (blockIdx.x / 3) * 2 + (role - 1);   // 0..CPYB-1
        const long NV4 = (long)NN * 32;                       // float4 per memory
        const long stride = (long)CPYB * 512;
        const long base = (long)cid * 512 + tid;
        const float4* mem4 = (const float4*)memory;
        float4* out4 = (float4*)out_mem;
#pragma unroll 1
        for (long i = base; i < NV4; i += 4 * stride) {
            long i0 = i, i1 = i + stride, i2 = i + 2 * stride, i3 = i + 3 * stride;
            if (winner[(int)(i0 >> 5)] < 0) out4[i0] = mem4[i0];
            if (i1 < NV4 && winner[(int)(i1 >> 5)] < 0) out4[i1] = mem4[i1];
            if (i2 < NV4 && winner[(int)(i2 >> 5)] < 0) out4[i2] = mem4[i2];
            if (i3 < NV4 && winner[(int)(i3 >> 5)] < 0) out4[i3] = mem4[i3];
        }
        if (base < NN) {
            int w = winner[(int)base];
            out_lu[base] = (w >= 0) ? ts[w] : lu_in[base];
        }
        return;
    }

    // ---------------- GRU role ----------------
    const int gid = blockIdx.x / 3;          // 0..GRUB-1
    const int rowBase = gid * RPB;

    for (int i = tid; i < RPB; i += 512) {
        int brow = rowBase + i;
        int nid = node_ids[brow];
        s_nid[i] = nid;
        s_win[i] = (winner[nid] == brow) ? 1 : 0;
    }
    __syncthreads();

    const int lane  = tid & 63;
    const int wave  = tid >> 6;
    const int l15   = lane & 15;
    const int khalf = lane >> 4;            // 0..3
    const int jcol  = wave * 16 + l15;      // this lane's output column

    // weight fragments (fp32 -> bf16), register-resident: 24 x bf16x8 = 96 VGPR
    bf16x8 wf[6][4];
#pragma unroll
    for (int g = 0; g < 3; ++g) {
#pragma unroll
        for (int ks = 0; ks < 4; ++ks) {
            const float* p = W_ih + (size_t)(g * 128 + jcol) * DD + ks * 32 + khalf * 8;
            wf[g][ks] = cvt8(*(const float4*)p, *(const float4*)(p + 4));
            const float* q = W_hh + (size_t)(g * 128 + jcol) * DD + ks * 32 + khalf * 8;
            wf[3 + g][ks] = cvt8(*(const float4*)q, *(const float4*)(q + 4));
        }
    }
    const float bir = b_ih[jcol], biz = b_ih[128 + jcol], bin = b_ih[256 + jcol];
    const float bhr = b_hh[jcol], bhz = b_hh[128 + jcol], bhn = b_hh[256 + jcol];

    // staging geometry: thread -> (row sr, 8-col chunk sc8), XOR-swizzled
    const int sr  = tid >> 4;               // 0..31
    const int sc8 = (tid & 15) * 8;         // 0..120
    const int ldsOff = sr * 256 + ((sc8 * 2) ^ ((sr & 7) << 4));

#define GLOAD(X0, X1, H0, H1, t)                                                \
    {                                                                           \
        int r_ = (t) * TR + sr;                                                 \
        const float* xp_ = messages + (size_t)(rowBase + r_) * DD + sc8;        \
        X0 = ((const float4*)xp_)[0]; X1 = ((const float4*)xp_)[1];             \
        const float* hp_ = memory + (size_t)s_nid[r_] * DD + sc8;               \
        H0 = ((const float4*)hp_)[0]; H1 = ((const float4*)hp_)[1];             \
    }

    auto compute_tile = [&](int buf, int t) {
#pragma unroll
        for (int sub = 0; sub < 2; ++sub) {
            const int arow = sub * 16 + l15;
            const char* xb = (const char*)(&x_lds[buf][0]) + arow * 256;
            const char* hb = (const char*)(&h_lds[buf][0]) + arow * 256;
            const int aswz = (arow & 7) << 4;
            bf16x8 ax[4], ah[4];
#pragma unroll
            for (int ks = 0; ks < 4; ++ks) {
                const int cb = (ks * 64 + khalf * 16) ^ aswz;
                ax[ks] = *(const bf16x8*)(xb + cb);
                ah[ks] = *(const bf16x8*)(hb + cb);
            }
            f32x4 a_ir = {0.f,0.f,0.f,0.f}, a_iz = a_ir, a_in = a_ir;
            f32x4 a_hr = a_ir, a_hz = a_ir, a_hn = a_ir;
#pragma unroll
            for (int ks = 0; ks < 4; ++ks) {
                a_ir = __builtin_amdgcn_mfma_f32_16x16x32_bf16(ax[ks], wf[0][ks], a_ir, 0, 0, 0);
                a_iz = __builtin_amdgcn_mfma_f32_16x16x32_bf16(ax[ks], wf[1][ks], a_iz, 0, 0, 0);
                a_in = __builtin_amdgcn_mfma_f32_16x16x32_bf16(ax[ks], wf[2][ks], a_in, 0, 0, 0);
                a_hr = __builtin_amdgcn_mfma_f32_16x16x32_bf16(ah[ks], wf[3][ks], a_hr, 0, 0, 0);
                a_hz = __builtin_amdgcn_mfma_f32_16x16x32_bf16(ah[ks], wf[4][ks], a_hz, 0, 0, 0);
                a_hn = __builtin_amdgcn_mfma_f32_16x16x32_bf16(ah[ks], wf[5][ks], a_hn, 0, 0, 0);
            }
#pragma unroll
            for (int q = 0; q < 4; ++q) {
                const int rl = sub * 16 + khalf * 4 + q;   // row within tile
                const int tr = t * TR + rl;                // row within block
                float rg = sigmoid_f(a_ir[q] + bir + a_hr[q] + bhr);
                float zg = sigmoid_f(a_iz[q] + biz + a_hz[q] + bhz);
                float ng = tanh_f(a_in[q] + bin + rg * (a_hn[q] + bhn));
                unsigned short hu = *(const unsigned short*)(
                    (const char*)(&h_lds[buf][0]) + rl * 256 + ((jcol * 2) ^ ((rl & 7) << 4)));
                float h = bf2f(hu);
                float hnew = (1.0f - zg) * ng + zg * h;
                if (s_win[tr]) out_mem[(size_t)s_nid[tr] * DD + jcol] = hnew;
            }
        }
    };

    // prefetch depth 2: two named register sets (static indexing)
    float4 xA0, xA1, hA0, hA1, xB0, xB1, hB0, hB1;
    GLOAD(xA0, xA1, hA0, hA1, 0);
    GLOAD(xB0, xB1, hB0, hB1, 1);

#pragma unroll 1
    for (int tp = 0; tp < NT; tp += 2) {
        // ---- tile tp: buffer 0, set A ----
        *(bf16x8*)((char*)(&x_lds[0][0]) + ldsOff) = cvt8(xA0, xA1);
        *(bf16x8*)((char*)(&h_lds[0][0]) + ldsOff) = cvt8(hA0, hA1);
        if (tp + 2 < NT) GLOAD(xA0, xA1, hA0, hA1, tp + 2);
        asm volatile("s_waitcnt lgkmcnt(0)" ::: "memory");
        __builtin_amdgcn_sched_barrier(0);
        __builtin_amdgcn_s_barrier();
        __builtin_amdgcn_sched_barrier(0);
        compute_tile(0, tp);

        // ---- tile tp+1: buffer 1, set B ----
        *(bf16x8*)((char*)(&x_lds[1][0]) + ldsOff) = cvt8(xB0, xB1);
        *(bf16x8*)((char*)(&h_lds[1][0]) + ldsOff) = cvt8(hB0, hB1);
        if (tp + 3 < NT) GLOAD(xB0, xB1, hB0, hB1, tp + 3);
        asm volatile("s_waitcnt lgkmcnt(0)" ::: "memory");
        __builtin_amdgcn_sched_barrier(0);
        __builtin_amdgcn_s_barrier();
        __builtin_amdgcn_sched_barrier(0);
        compute_tile(1, tp + 1);
    }
#undef GLOAD
}

// ---------------------------------------------------------------------------
extern "C" void kernel_launch(void* const* d_in, const int* in_sizes, int n_in,
                              void* d_out, int out_size, void* d_ws, size_t ws_size,
                              hipStream_t stream) {
    const float* memory      = (const float*)d_in[0];
    const float* last_update = (const float*)d_in[1];
    const float* messages    = (const float*)d_in[2];
    const float* timestamps  = (const float*)d_in[3];
    const float* W_ih        = (const float*)d_in[4];
    const float* W_hh        = (const float*)d_in[5];
    const float* b_ih        = (const float*)d_in[6];
    const float* b_hh        = (const float*)d_in[7];
    const int*   node_ids    = (const int*)d_in[8];

    float* out_mem = (float*)d_out;
    float* out_lu  = out_mem + (size_t)NN * DD;

    int* winner = (int*)d_ws;

    k_init<<<(NN / 4 + 255) / 256, 256, 0, stream>>>((int4*)winner);
    k_winner<<<BT / 256, 256, 0, stream>>>(node_ids, winner);
    k_fused<<<GRID, 512, 0, stream>>>(memory, messages, W_ih, W_hh, b_ih, b_hh,
                                      node_ids, winner, last_update, timestamps,
                                      out_mem, out_lu);
}